// Round 1
// baseline (602.015 us; speedup 1.0000x reference)
//
#include <hip/hip_runtime.h>

// Fused 3D window attention (Swin-style) + 1x1 conv for MI355X (gfx950).
// One workgroup (256 thr = 4 waves) per 4x4x4 window; 4096 windows.
// All GEMM-shaped math in bf16 MFMA (16x16x32), fp32 accumulate.

#define NHEAD 8
#define HDIM 16
#define CCH 128
#define DD0 30
#define HH0 62
#define WW0 126
#define SD 7812      // HH0*WW0
#define SC 234360    // DD0*SD

typedef __bf16 bfx8 __attribute__((ext_vector_type(8)));
typedef float  fx4  __attribute__((ext_vector_type(4)));

__device__ __forceinline__ fx4 MFMA(bfx8 a, bfx8 b, fx4 c) {
    return __builtin_amdgcn_mfma_f32_16x16x32_bf16(a, b, c, 0, 0, 0);
}

__device__ __forceinline__ fx4 fzero4() { fx4 v = {0.f, 0.f, 0.f, 0.f}; return v; }
__device__ __forceinline__ bfx8 bzero8() {
    bfx8 v;
    #pragma unroll
    for (int j = 0; j < 8; j++) v[j] = (__bf16)0.f;
    return v;
}

// Cast weights to bf16. Row-major qkv_w[oc][c] / conv_w[o][c] IS the packed
// B-operand layout: B-frag lane reads 8 contiguous k at Bq[(n*16+kg)*8].
__global__ void prep_kernel(const float* __restrict__ qkv_w,
                            const float* __restrict__ conv_w,
                            __bf16* __restrict__ Bq, __bf16* __restrict__ Bc) {
    const int i = blockIdx.x * 256 + threadIdx.x;   // grid covers 65536 exactly
    if (i < 49152) Bq[i] = (__bf16)qkv_w[i];
    else            Bc[i - 49152] = (__bf16)conv_w[i - 49152];
}

__global__ __launch_bounds__(256, 2) void winattn_kernel(
    const float* __restrict__ x,
    const float* __restrict__ qkv_b,
    const float* __restrict__ conv_b,
    const __bf16* __restrict__ Bq,
    const __bf16* __restrict__ Bc,
    float* __restrict__ out)
{
    // 64 KB LDS, three-way reuse:
    //  [0,16K):  x-tile [64][128] bf16 (chunk-XOR swizzle) -> per-wave P staging -> attn-out tile
    //  [16K,64K): q [8][64][16] | k (+8192 elem) | v^T [8][16][64] (+16384 elem); later fp32 fin[128][68]
    __shared__ __align__(16) unsigned char lds_raw[65536];
    __bf16* xsb  = (__bf16*)lds_raw;
    __bf16* qkvs = (__bf16*)(lds_raw + 16384);
    float*  fin  = (float*)(lds_raw + 16384);

    const int tid  = threadIdx.x;
    const int wave = tid >> 6;
    const int lane = tid & 63;
    const int quad = lane >> 4;
    const int l15  = lane & 15;

    const int blk = blockIdx.x;
    const int Db = (blk >> 9) << 2;
    const int Hb = ((blk >> 5) & 15) << 2;
    const int Wb = (blk & 31) << 2;

    // pad-mask bit per token (token index == lane); token l = bd*16+bh*4+bw
    unsigned long long pmask;
    {
        const bool p = (Db + (lane >> 4) >= DD0) || (Hb + ((lane >> 2) & 3) >= HH0) ||
                       (Wb + (lane & 3) >= WW0);
        pmask = __ballot(p);
    }

    // ---- stage x window tile -> LDS bf16, swizzled: phys_chunk = (c>>3) ^ (l&15) ----
    {
        const int l = tid & 63;
        const int Dg = Db + (l >> 4), Hg = Hb + ((l >> 2) & 3), Wg = Wb + (l & 3);
        const bool ok = (Dg < DD0) && (Hg < HH0) && (Wg < WW0);
        const int xoff = Dg * SD + Hg * WW0 + Wg;
        const int swz = l & 15;
        const int c0 = tid >> 6;
        #pragma unroll
        for (int cc = 0; cc < 32; cc++) {
            const int c = cc * 4 + c0;
            const float v = ok ? x[c * SC + xoff] : 0.f;
            xsb[l * 128 + ((c >> 3) ^ swz) * 8 + (c & 7)] = (__bf16)v;
        }
    }
    __syncthreads();

    // ---- QKV: (64x128)@(128x384); wave owns 96 output cols ----
    {
        fx4 acc[4][6];
        #pragma unroll
        for (int mt = 0; mt < 4; mt++)
            #pragma unroll
            for (int nt = 0; nt < 6; nt++) acc[mt][nt] = fzero4();
        const int nbase = wave * 96;
        #pragma unroll
        for (int ks = 0; ks < 4; ks++) {
            bfx8 a[4];
            #pragma unroll
            for (int mt = 0; mt < 4; mt++) {
                const int m = mt * 16 + l15;
                const int phys = (ks * 4 + quad) ^ (m & 15);
                a[mt] = *(const bfx8*)(xsb + m * 128 + phys * 8);
            }
            #pragma unroll
            for (int nt = 0; nt < 6; nt++) {
                const int n = nbase + nt * 16 + l15;
                const bfx8 bb = *(const bfx8*)(Bq + (n * 16 + ks * 4 + quad) * 8);
                #pragma unroll
                for (int mt = 0; mt < 4; mt++) acc[mt][nt] = MFMA(a[mt], bb, acc[mt][nt]);
            }
        }
        // epilogue: +bias, q*=scale(0.25, exact), scatter to q/k/v LDS
        #pragma unroll
        for (int nt = 0; nt < 6; nt++) {
            const int col = nbase + nt * 16 + l15;
            const float bias = qkv_b[col];
            const int s = col >> 7, hh = (col >> 4) & 7, e = col & 15;
            #pragma unroll
            for (int mt = 0; mt < 4; mt++) {
                #pragma unroll
                for (int r = 0; r < 4; r++) {
                    const int tok = mt * 16 + quad * 4 + r;
                    float v = acc[mt][nt][r] + bias;
                    if (s == 0) v *= 0.25f;
                    if (s < 2) {   // q,k: [head][tok][16], swizzle on 2 chunks
                        const int phys = (e >> 3) ^ ((tok >> 2) & 1);
                        qkvs[s * 8192 + hh * 1024 + tok * 16 + phys * 8 + (e & 7)] = (__bf16)v;
                    } else {       // v^T: [head][hd][64], swizzle on 8 chunks
                        const int phys = (tok >> 3) ^ (e & 7);
                        qkvs[16384 + hh * 1024 + e * 64 + phys * 8 + (tok & 7)] = (__bf16)v;
                    }
                }
            }
        }
    }
    __syncthreads();

    // ---- attention: wave w handles heads w and w+4 ----
    fx4 ovec[2][4];
    __bf16* ps = xsb + wave * 2048;   // per-wave [64][32] P staging (x-tile region, dead now)
    #pragma unroll
    for (int hi = 0; hi < 2; hi++) {
        const int hh = wave + hi * 4;
        fx4 lg[4][4];
        #pragma unroll
        for (int mt = 0; mt < 4; mt++)
            #pragma unroll
            for (int nt = 0; nt < 4; nt++) lg[mt][nt] = fzero4();

        // QK^T: K=32 MFMA, k>=16 zeroed in both operands (hd=16)
        bfx8 aq[4], bk[4];
        #pragma unroll
        for (int mt = 0; mt < 4; mt++) {
            aq[mt] = bzero8();
            if (quad < 2) {
                const int m = mt * 16 + l15;
                const int phys = quad ^ ((m >> 2) & 1);
                aq[mt] = *(const bfx8*)(qkvs + hh * 1024 + m * 16 + phys * 8);
            }
        }
        #pragma unroll
        for (int nt = 0; nt < 4; nt++) {
            bk[nt] = bzero8();
            if (quad < 2) {
                const int n = nt * 16 + l15;
                const int phys = quad ^ ((n >> 2) & 1);
                bk[nt] = *(const bfx8*)(qkvs + 8192 + hh * 1024 + n * 16 + phys * 8);
            }
        }
        #pragma unroll
        for (int mt = 0; mt < 4; mt++)
            #pragma unroll
            for (int nt = 0; nt < 4; nt++) lg[mt][nt] = MFMA(aq[mt], bk[nt], lg[mt][nt]);

        // masked softmax, no max-sub (logits O(0.3); ref's -1000 underflows to exact 0)
        #pragma unroll
        for (int mt = 0; mt < 4; mt++) {
            float sum[4] = {0.f, 0.f, 0.f, 0.f};
            #pragma unroll
            for (int nt = 0; nt < 4; nt++) {
                const unsigned cb = (unsigned)(pmask >> (nt * 16 + l15)) & 1u;
                #pragma unroll
                for (int r = 0; r < 4; r++) {
                    const unsigned rb = (unsigned)(pmask >> (mt * 16 + quad * 4 + r)) & 1u;
                    const float e = (rb ^ cb) ? 0.f : __expf(lg[mt][nt][r]);
                    lg[mt][nt][r] = e;
                    sum[r] += e;
                }
            }
            #pragma unroll
            for (int r = 0; r < 4; r++) {
                float s = sum[r];
                s += __shfl_xor(s, 1);
                s += __shfl_xor(s, 2);
                s += __shfl_xor(s, 4);
                s += __shfl_xor(s, 8);   // row-sum across the 16 lanes of this quad
                const float rinv = __builtin_amdgcn_rcpf(s);
                #pragma unroll
                for (int nt = 0; nt < 4; nt++) lg[mt][nt][r] *= rinv;
            }
        }

        // P@V, P staged in two 64x32 halves (same-wave DS ops are in-order: no barrier)
        #pragma unroll
        for (int mt = 0; mt < 4; mt++) ovec[hi][mt] = fzero4();
        #pragma unroll
        for (int half = 0; half < 2; half++) {
            #pragma unroll
            for (int nn = 0; nn < 2; nn++) {
                const int nt = half * 2 + nn;
                const int ccol = nn * 16 + l15;
                #pragma unroll
                for (int mt = 0; mt < 4; mt++)
                    #pragma unroll
                    for (int r = 0; r < 4; r++) {
                        const int tok = mt * 16 + quad * 4 + r;
                        const int phys = (ccol >> 3) ^ ((tok >> 1) & 3);
                        ps[tok * 32 + phys * 8 + (ccol & 7)] = (__bf16)lg[mt][nt][r];
                    }
            }
            bfx8 bv;
            {
                const int phys = (half * 4 + quad) ^ (l15 & 7);
                bv = *(const bfx8*)(qkvs + 16384 + hh * 1024 + l15 * 64 + phys * 8);
            }
            #pragma unroll
            for (int mt = 0; mt < 4; mt++) {
                const int m = mt * 16 + l15;
                const int phys = quad ^ ((m >> 1) & 3);
                const bfx8 ap = *(const bfx8*)(ps + m * 32 + phys * 8);
                ovec[hi][mt] = MFMA(ap, bv, ovec[hi][mt]);
            }
        }
    }
    __syncthreads();   // all P/qkv reads done; x-tile region reusable as attn-out

    // ---- attn-out tile -> LDS bf16 (same swizzle as x-tile) ----
    #pragma unroll
    for (int hi = 0; hi < 2; hi++) {
        const int hh = wave + hi * 4;
        #pragma unroll
        for (int mt = 0; mt < 4; mt++)
            #pragma unroll
            for (int r = 0; r < 4; r++) {
                const int tok = mt * 16 + quad * 4 + r;
                const int ch = hh * 16 + l15;
                const int phys = (ch >> 3) ^ (tok & 15);
                xsb[tok * 128 + phys * 8 + (ch & 7)] = (__bf16)ovec[hi][mt][r];
            }
    }
    __syncthreads();

    // ---- 1x1 conv: (64x128)@(128x128); wave owns 32 cols; fin overlays dead q/k/v ----
    {
        fx4 cacc[4][2];
        #pragma unroll
        for (int mt = 0; mt < 4; mt++)
            #pragma unroll
            for (int nt = 0; nt < 2; nt++) cacc[mt][nt] = fzero4();
        const int nb2 = wave * 32;
        #pragma unroll
        for (int ks = 0; ks < 4; ks++) {
            bfx8 a[4];
            #pragma unroll
            for (int mt = 0; mt < 4; mt++) {
                const int m = mt * 16 + l15;
                const int phys = (ks * 4 + quad) ^ (m & 15);
                a[mt] = *(const bfx8*)(xsb + m * 128 + phys * 8);
            }
            #pragma unroll
            for (int nt = 0; nt < 2; nt++) {
                const int n = nb2 + nt * 16 + l15;
                const bfx8 bb = *(const bfx8*)(Bc + (n * 16 + ks * 4 + quad) * 8);
                #pragma unroll
                for (int mt = 0; mt < 4; mt++) cacc[mt][nt] = MFMA(a[mt], bb, cacc[mt][nt]);
            }
        }
        #pragma unroll
        for (int nt = 0; nt < 2; nt++) {
            const int col = nb2 + nt * 16 + l15;
            const float cb = conv_b[col];
            #pragma unroll
            for (int mt = 0; mt < 4; mt++)
                #pragma unroll
                for (int r = 0; r < 4; r++) {
                    const int tok = mt * 16 + quad * 4 + r;
                    fin[col * 68 + tok] = cacc[mt][nt][r] + cb;   // stride 68: 2-way banks
                }
        }
    }
    __syncthreads();

    // ---- cropped output write: per (o,bd,bh) a 4-float W-run ----
    {
        const int bd = (tid >> 2) & 3, bh = tid & 3;
        const int Dg = Db + bd, Hg = Hb + bh;
        const bool ok = (Dg < DD0) && (Hg < HH0);
        const bool w2ok = (Wb + 2 < WW0);
        const int spoff = Dg * SD + Hg * WW0 + Wb;
        const int finoff = bd * 16 + bh * 4;
        const int o0 = tid >> 4;
        if (ok) {
            #pragma unroll
            for (int oo = 0; oo < 8; oo++) {
                const int o = oo * 16 + o0;
                const float4 v = *(const float4*)(fin + o * 68 + finoff);
                const int base = o * SC + spoff;
                out[base]     = v.x;
                out[base + 1] = v.y;
                if (w2ok) { out[base + 2] = v.z; out[base + 3] = v.w; }
            }
        }
    }
}

extern "C" void kernel_launch(void* const* d_in, const int* in_sizes, int n_in,
                              void* d_out, int out_size, void* d_ws, size_t ws_size,
                              hipStream_t stream) {
    const float* x      = (const float*)d_in[0];
    const float* qkv_w  = (const float*)d_in[1];
    const float* qkv_b  = (const float*)d_in[2];
    const float* conv_w = (const float*)d_in[3];
    const float* conv_b = (const float*)d_in[4];
    float* out = (float*)d_out;

    __bf16* Bq = (__bf16*)d_ws;                       // 384*128 bf16
    __bf16* Bc = (__bf16*)((char*)d_ws + 98304);      // 128*128 bf16

    prep_kernel<<<256, 256, 0, stream>>>(qkv_w, conv_w, Bq, Bc);
    winattn_kernel<<<4096, 256, 0, stream>>>(x, qkv_b, conv_b, Bq, Bc, out);
}

// Round 2
// 441.335 us; speedup vs baseline: 1.3641x; 1.3641x over previous
//
#include <hip/hip_runtime.h>

// Fused 3D window attention (Swin-style) + 1x1 conv for MI355X (gfx950).
// One workgroup (256 thr = 4 waves) per 4x4x4 window; 4096 windows.
// bf16 MFMA 16x16x32, fp32 accumulate. 32 KB LDS -> 4-5 blocks/CU.
// XCD-aware block swizzle: W-adjacent windows share an XCD's L2.

#define NHEAD 8
#define HDIM 16
#define CCH 128
#define DD0 30
#define HH0 62
#define WW0 126
#define SD 7812      // HH0*WW0
#define SC 234360    // DD0*SD

typedef __bf16 bfx8 __attribute__((ext_vector_type(8)));
typedef float  fx4  __attribute__((ext_vector_type(4)));
typedef float  fx2  __attribute__((ext_vector_type(2)));

__device__ __forceinline__ fx4 MFMA(bfx8 a, bfx8 b, fx4 c) {
    return __builtin_amdgcn_mfma_f32_16x16x32_bf16(a, b, c, 0, 0, 0);
}
__device__ __forceinline__ fx4 fzero4() { fx4 v = {0.f, 0.f, 0.f, 0.f}; return v; }
__device__ __forceinline__ bfx8 bzero8() {
    bfx8 v;
    #pragma unroll
    for (int j = 0; j < 8; j++) v[j] = (__bf16)0.f;
    return v;
}
__device__ __forceinline__ unsigned pk2(float a, float b) {
    __bf16 ax = (__bf16)a, by = (__bf16)b;
    unsigned short ua = __builtin_bit_cast(unsigned short, ax);
    unsigned short ub = __builtin_bit_cast(unsigned short, by);
    return (unsigned)ua | ((unsigned)ub << 16);
}

// Cast weights to bf16. Row-major qkv_w[oc][c] / conv_w[o][c] IS the packed
// B-operand layout: B-frag lane reads 8 contiguous k at Bq[(n*16+kg)*8].
__global__ void prep_kernel(const float* __restrict__ qkv_w,
                            const float* __restrict__ conv_w,
                            __bf16* __restrict__ Bq, __bf16* __restrict__ Bc) {
    const int i = blockIdx.x * 256 + threadIdx.x;   // grid covers 65536 exactly
    if (i < 49152) Bq[i] = (__bf16)qkv_w[i];
    else            Bc[i - 49152] = (__bf16)conv_w[i - 49152];
}

__global__ __launch_bounds__(256, 4) void winattn_kernel(
    const float* __restrict__ x,
    const float* __restrict__ qkv_b,
    const float* __restrict__ conv_b,
    const __bf16* __restrict__ Bq,
    const __bf16* __restrict__ Bc,
    float* __restrict__ out)
{
    // 32 KB LDS:
    //  R0 [0,16K):  x-tile [64][128] -> q slots [8][64][16] -> attn-out head stripes
    //  R1 [16K,32K): k slots [8][64][16]; q/k slots double as per-wave P staging
    __shared__ __align__(16) unsigned char lds_raw[32768];
    __bf16* ldsQ = (__bf16*)lds_raw;             // also x-tile
    __bf16* ldsK = (__bf16*)(lds_raw + 16384);

    const int tid  = threadIdx.x;
    const int wave = tid >> 6;
    const int lane = tid & 63;
    const int quad = lane >> 4;
    const int l15  = lane & 15;

    // XCD swizzle: blocks round-robin over 8 XCDs; give each XCD a contiguous
    // 512-window slab so W-adjacent windows (sharing 64B lines) are L2-local.
    const int blk = blockIdx.x;
    const int wid = ((blk & 7) << 9) | (blk >> 3);
    const int Db = (wid >> 9) << 2;
    const int Hb = ((wid >> 5) & 15) << 2;
    const int Wb = (wid & 31) << 2;

    // pad-mask bit per token (token index == lane); token l = bd*16+bh*4+bw
    unsigned long long pmask;
    {
        const bool p = (Db + (lane >> 4) >= DD0) || (Hb + ((lane >> 2) & 3) >= HH0) ||
                       (Wb + (lane & 3) >= WW0);
        pmask = __ballot(p);
    }

    // ---- stage x window tile -> R0 bf16, swizzle phys_chunk = (c>>3) ^ (tok&15) ----
    {
        #pragma unroll
        for (int it = 0; it < 16; it++) {
            const int u = it * 256 + tid;          // (c, dh, wpair)
            const int wp = u & 1;
            const int dh = (u >> 1) & 15;
            const int c  = u >> 5;
            const int Dg = Db + (dh >> 2), Hg = Hb + (dh & 3);
            const bool valid = (Dg < DD0) && (Hg < HH0) && (wp == 0 || Wb < 124);
            fx2 v = {0.f, 0.f};
            if (valid) v = *(const fx2*)(x + c * SC + Dg * SD + Hg * WW0 + Wb + wp * 2);
            const int tok0 = dh * 4 + wp * 2;
            ldsQ[tok0 * 128 + (((c >> 3) ^ (tok0 & 15)) << 3) + (c & 7)] = (__bf16)v[0];
            const int tok1 = tok0 + 1;
            ldsQ[tok1 * 128 + (((c >> 3) ^ (tok1 & 15)) << 3) + (c & 7)] = (__bf16)v[1];
        }
    }
    __syncthreads();   // b1

    unsigned vpk[2][4][2];   // v (head wave+4*hi) packed bf16: [hi][mt][r-pair]

    // ---- QKV group 0: k(w), k(w+4), v(w), v(w+4)  (wave-private heads) ----
    {
        fx4 acc[4][4];
        #pragma unroll
        for (int mt = 0; mt < 4; mt++)
            #pragma unroll
            for (int j = 0; j < 4; j++) acc[mt][j] = fzero4();
        #pragma unroll
        for (int ks = 0; ks < 4; ks++) {
            bfx8 a[4];
            #pragma unroll
            for (int mt = 0; mt < 4; mt++) {
                const int m = mt * 16 + l15;
                const int phys = (ks * 4 + quad) ^ (m & 15);
                a[mt] = *(const bfx8*)(ldsQ + m * 128 + phys * 8);
            }
            #pragma unroll
            for (int j = 0; j < 4; j++) {
                const int col = (1 + (j >> 1)) * 128 + (wave + (j & 1) * 4) * 16 + l15;
                const bfx8 bb = *(const bfx8*)(Bq + (col * 16 + ks * 4 + quad) * 8);
                #pragma unroll
                for (int mt = 0; mt < 4; mt++) acc[mt][j] = MFMA(a[mt], bb, acc[mt][j]);
            }
        }
        // k -> R1 slots (no conflict with x in R0: no barrier needed)
        #pragma unroll
        for (int j = 0; j < 2; j++) {
            const int hh = wave + j * 4;
            const float bias = qkv_b[128 + hh * 16 + l15];
            #pragma unroll
            for (int mt = 0; mt < 4; mt++)
                #pragma unroll
                for (int r = 0; r < 4; r++) {
                    const int tok = mt * 16 + quad * 4 + r;
                    const int phys = (l15 >> 3) ^ ((tok >> 2) & 1);
                    ldsK[hh * 1024 + tok * 16 + phys * 8 + (l15 & 7)] =
                        (__bf16)(acc[mt][j][r] + bias);
                }
        }
        // v -> registers, packed bf16
        #pragma unroll
        for (int hi = 0; hi < 2; hi++) {
            const float bias = qkv_b[256 + (wave + hi * 4) * 16 + l15];
            #pragma unroll
            for (int mt = 0; mt < 4; mt++) {
                vpk[hi][mt][0] = pk2(acc[mt][2 + hi][0] + bias, acc[mt][2 + hi][1] + bias);
                vpk[hi][mt][1] = pk2(acc[mt][2 + hi][2] + bias, acc[mt][2 + hi][3] + bias);
            }
        }
    }

    // ---- QKV group 1: q(w), q(w+4) ----
    {
        fx4 acc[4][2];
        #pragma unroll
        for (int mt = 0; mt < 4; mt++)
            #pragma unroll
            for (int hi = 0; hi < 2; hi++) acc[mt][hi] = fzero4();
        #pragma unroll
        for (int ks = 0; ks < 4; ks++) {
            bfx8 a[4];
            #pragma unroll
            for (int mt = 0; mt < 4; mt++) {
                const int m = mt * 16 + l15;
                const int phys = (ks * 4 + quad) ^ (m & 15);
                a[mt] = *(const bfx8*)(ldsQ + m * 128 + phys * 8);
            }
            #pragma unroll
            for (int hi = 0; hi < 2; hi++) {
                const int col = (wave + hi * 4) * 16 + l15;
                const bfx8 bb = *(const bfx8*)(Bq + (col * 16 + ks * 4 + quad) * 8);
                #pragma unroll
                for (int mt = 0; mt < 4; mt++) acc[mt][hi] = MFMA(a[mt], bb, acc[mt][hi]);
            }
        }
        __syncthreads();   // b2: all x-tile reads done; R0 becomes q slots
        #pragma unroll
        for (int hi = 0; hi < 2; hi++) {
            const int hh = wave + hi * 4;
            const float bias = qkv_b[hh * 16 + l15];
            #pragma unroll
            for (int mt = 0; mt < 4; mt++)
                #pragma unroll
                for (int r = 0; r < 4; r++) {
                    const int tok = mt * 16 + quad * 4 + r;
                    const int phys = (l15 >> 3) ^ ((tok >> 2) & 1);
                    ldsQ[hh * 1024 + tok * 16 + phys * 8 + (l15 & 7)] =
                        (__bf16)((acc[mt][hi][r] + bias) * 0.25f);   // scale = hd^-0.5
                }
        }
    }
    __syncthreads();   // b3

    // ---- attention: wave w handles heads w and w+4 (fully wave-private) ----
    const int srcA = ((((quad << 1) + 0) & 3) << 4) | l15;
    const int srcB = ((((quad << 1) + 1) & 3) << 4) | l15;
    #pragma unroll
    for (int hi = 0; hi < 2; hi++) {
        const int hh = wave + hi * 4;
        __bf16* qs = ldsQ + hh * 1024;   // [64][16] q slot -> P piece 0 -> out stripe
        __bf16* kk = ldsK + hh * 1024;   // [64][16] k slot -> P piece 1

        fx4 lg[4][4];
        #pragma unroll
        for (int mt = 0; mt < 4; mt++)
            #pragma unroll
            for (int nt = 0; nt < 4; nt++) lg[mt][nt] = fzero4();

        // QK^T (K=32 MFMA, hd=16: quads 2,3 zero in regs)
        bfx8 aq[4];
        #pragma unroll
        for (int mt = 0; mt < 4; mt++) {
            aq[mt] = bzero8();
            if (quad < 2) {
                const int m = mt * 16 + l15;
                const int phys = quad ^ ((m >> 2) & 1);
                aq[mt] = *(const bfx8*)(qs + m * 16 + phys * 8);
            }
        }
        #pragma unroll
        for (int nt = 0; nt < 4; nt++) {
            bfx8 bk = bzero8();
            if (quad < 2) {
                const int n = nt * 16 + l15;
                const int phys = quad ^ ((n >> 2) & 1);
                bk = *(const bfx8*)(kk + n * 16 + phys * 8);
            }
            #pragma unroll
            for (int mt = 0; mt < 4; mt++) lg[mt][nt] = MFMA(aq[mt], bk, lg[mt][nt]);
        }

        // masked softmax (no max-sub: logits O(1); ref's -1000 underflows to 0)
        #pragma unroll
        for (int mt = 0; mt < 4; mt++) {
            float sum[4] = {0.f, 0.f, 0.f, 0.f};
            #pragma unroll
            for (int nt = 0; nt < 4; nt++) {
                const unsigned cb = (unsigned)(pmask >> (nt * 16 + l15)) & 1u;
                #pragma unroll
                for (int r = 0; r < 4; r++) {
                    const unsigned rb = (unsigned)(pmask >> (mt * 16 + quad * 4 + r)) & 1u;
                    const float e = (rb ^ cb) ? 0.f : __expf(lg[mt][nt][r]);
                    lg[mt][nt][r] = e;
                    sum[r] += e;
                }
            }
            #pragma unroll
            for (int r = 0; r < 4; r++) {
                float s = sum[r];
                s += __shfl_xor(s, 1);
                s += __shfl_xor(s, 2);
                s += __shfl_xor(s, 4);
                s += __shfl_xor(s, 8);   // row-sum across the 16 lanes of this quad
                const float rinv = __builtin_amdgcn_rcpf(s);
                #pragma unroll
                for (int nt = 0; nt < 4; nt++) lg[mt][nt][r] *= rinv;
            }
        }

        // P@V. P staged per 32-token half into dead q/k slots (wave-private,
        // same-wave DS ordering => no barrier). V B-frag built by shuffles.
        fx4 ovec[4];
        #pragma unroll
        for (int mt = 0; mt < 4; mt++) ovec[mt] = fzero4();
        #pragma unroll
        for (int half = 0; half < 2; half++) {
            #pragma unroll
            for (int nn = 0; nn < 2; nn++) {
                __bf16* piece = nn ? kk : qs;
                const int nt = half * 2 + nn;
                #pragma unroll
                for (int mt = 0; mt < 4; mt++)
                    #pragma unroll
                    for (int r = 0; r < 4; r++) {
                        const int tok = mt * 16 + quad * 4 + r;
                        const int phys = (l15 >> 3) ^ ((tok >> 2) & 1);
                        piece[tok * 16 + phys * 8 + (l15 & 7)] = (__bf16)lg[mt][nt][r];
                    }
            }
            // bv[j] = v[half*32 + quad*8 + j][l15]; src lane (2q+t)&3, mt = half*2+(quad>>1)
            const unsigned a00 = (unsigned)__shfl((int)vpk[hi][half * 2 + 0][0], srcA);
            const unsigned a01 = (unsigned)__shfl((int)vpk[hi][half * 2 + 0][1], srcA);
            const unsigned a10 = (unsigned)__shfl((int)vpk[hi][half * 2 + 1][0], srcA);
            const unsigned a11 = (unsigned)__shfl((int)vpk[hi][half * 2 + 1][1], srcA);
            const unsigned b00 = (unsigned)__shfl((int)vpk[hi][half * 2 + 0][0], srcB);
            const unsigned b01 = (unsigned)__shfl((int)vpk[hi][half * 2 + 0][1], srcB);
            const unsigned b10 = (unsigned)__shfl((int)vpk[hi][half * 2 + 1][0], srcB);
            const unsigned b11 = (unsigned)__shfl((int)vpk[hi][half * 2 + 1][1], srcB);
            const bool mhi = quad >= 2;
            uint4 uv;
            uv.x = mhi ? a10 : a00;
            uv.y = mhi ? a11 : a01;
            uv.z = mhi ? b10 : b00;
            uv.w = mhi ? b11 : b01;
            const bfx8 bv = __builtin_bit_cast(bfx8, uv);
            #pragma unroll
            for (int mt = 0; mt < 4; mt++) {
                const int m = mt * 16 + l15;
                const int phys = (quad & 1) ^ ((m >> 2) & 1);
                const bfx8 ap = *(const bfx8*)(((quad >> 1) ? kk : qs) + m * 16 + phys * 8);
                ovec[mt] = MFMA(ap, bv, ovec[mt]);
            }
        }
        // attn-out head stripe -> q slot (dead; wave-private, in-order)
        #pragma unroll
        for (int mt = 0; mt < 4; mt++)
            #pragma unroll
            for (int r = 0; r < 4; r++) {
                const int tok = mt * 16 + quad * 4 + r;
                const int phys = (l15 >> 3) ^ ((tok >> 2) & 1);
                qs[tok * 16 + phys * 8 + (l15 & 7)] = (__bf16)ovec[mt][r];
            }
    }
    __syncthreads();   // b4: all stripes written; R0 = attn-out [8 stripes][64][16]

    // ---- 1x1 conv: (64x128)@(128x128); wave owns 32 cols; store from C-layout ----
    {
        fx4 cacc[4][2];
        #pragma unroll
        for (int mt = 0; mt < 4; mt++)
            #pragma unroll
            for (int nt = 0; nt < 2; nt++) cacc[mt][nt] = fzero4();
        #pragma unroll
        for (int ks = 0; ks < 4; ks++) {
            const int kg = ks * 4 + quad;          // channel chunk = head stripe kg>>1
            bfx8 a[4];
            #pragma unroll
            for (int mt = 0; mt < 4; mt++) {
                const int m = mt * 16 + l15;
                const int phys = (kg & 1) ^ ((m >> 2) & 1);
                a[mt] = *(const bfx8*)(ldsQ + (kg >> 1) * 1024 + m * 16 + phys * 8);
            }
            #pragma unroll
            for (int nt = 0; nt < 2; nt++) {
                const int o = wave * 32 + nt * 16 + l15;
                const bfx8 bb = *(const bfx8*)(Bc + (o * 16 + kg) * 8);
                #pragma unroll
                for (int mt = 0; mt < 4; mt++) cacc[mt][nt] = MFMA(a[mt], bb, cacc[mt][nt]);
            }
        }
        // C-layout: cacc[mt][nt][r] = out[o=..][D=Db+mt][H=Hb+quad][W=Wb+r]
        #pragma unroll
        for (int nt = 0; nt < 2; nt++) {
            const int o = wave * 32 + nt * 16 + l15;
            const float cb = conv_b[o];
            #pragma unroll
            for (int mt = 0; mt < 4; mt++) {
                if (Db + mt < DD0) {
                    const int Hg = Hb + quad;
                    if (Hg < HH0) {
                        const int base = o * SC + (Db + mt) * SD + Hg * WW0 + Wb;
                        fx2 w0 = {cacc[mt][nt][0] + cb, cacc[mt][nt][1] + cb};
                        *(fx2*)(out + base) = w0;
                        if (Wb < 124) {
                            fx2 w1 = {cacc[mt][nt][2] + cb, cacc[mt][nt][3] + cb};
                            *(fx2*)(out + base + 2) = w1;
                        }
                    }
                }
            }
        }
    }
}

extern "C" void kernel_launch(void* const* d_in, const int* in_sizes, int n_in,
                              void* d_out, int out_size, void* d_ws, size_t ws_size,
                              hipStream_t stream) {
    const float* x      = (const float*)d_in[0];
    const float* qkv_w  = (const float*)d_in[1];
    const float* qkv_b  = (const float*)d_in[2];
    const float* conv_w = (const float*)d_in[3];
    const float* conv_b = (const float*)d_in[4];
    float* out = (float*)d_out;

    __bf16* Bq = (__bf16*)d_ws;                       // 384*128 bf16
    __bf16* Bc = (__bf16*)((char*)d_ws + 98304);      // 128*128 bf16

    prep_kernel<<<256, 256, 0, stream>>>(qkv_w, conv_w, Bq, Bc);
    winattn_kernel<<<4096, 256, 0, stream>>>(x, qkv_b, conv_b, Bq, Bc, out);
}